// Round 10
// baseline (1896.283 us; speedup 1.0000x reference)
//
#include <hip/hip_runtime.h>
#include <math.h>

// Problem constants
#define BB   4
#define SS   96
#define NN   512
#define DD   8
#define HH   64
#define G4   256    // 4*H
#define OUTK 24

#define THREADS 512
#define AST     580   // a_lds row stride
#define AHWS    516   // u_lds per-wave stride
#define CSTR    64    // u32 stride per batch counter (256 B line)
#define BARSZ   (BB * CSTR)

typedef float f32x4 __attribute__((ext_vector_type(4)));

// ---------------------------------------------------------------------------
__global__ void bar_init(unsigned* __restrict__ bar) {
    const int i = blockIdx.x * 256 + threadIdx.x;
    if (i < BARSZ) bar[i] = 0u;
}

__device__ __forceinline__ float sigm_f(float v) { return 1.f / (1.f + __expf(-v)); }
__device__ __forceinline__ float tanh_f(float v) { return 1.f - 2.f / (__expf(2.f * v) + 1.f); }

__device__ __forceinline__ void vfma(f32x4& d, float s, f32x4 v) {
    d.x = fmaf(s, v.x, d.x); d.y = fmaf(s, v.y, d.y);
    d.z = fmaf(s, v.z, d.z); d.w = fmaf(s, v.w, d.w);
}

// ---------------------------------------------------------------------------
// RPB = adj rows owned per block. RPB=8: 256 blocks (1/CU, proven R6 config).
// RPB=4: 512 blocks (2/CU; CU pairs are different batches -> decorrelated
// stall windows). Structure/FP order identical; only the partition changes.
template<int RPB>
__global__ __launch_bounds__(THREADS, 4) void gnn_lstm_persist(
    const float* __restrict__ x,    // [B][S][N][D]
    const float* __restrict__ adj,  // [B][S][N][N]
    const float* __restrict__ h0,   // [B][N][H]
    const float* __restrict__ c0,   // [B][N][H]
    const float* __restrict__ Wx,   // [D][256]
    const float* __restrict__ Wh,   // [H][256]
    const float* __restrict__ bg,   // [256]
    const float* __restrict__ W1, const float* __restrict__ b1,
    const float* __restrict__ W2, const float* __restrict__ b2,
    float* __restrict__ out,        // [4][24]
    float* __restrict__ hA, float* __restrict__ hB,
    unsigned* __restrict__ bar)
{
    constexpr int BPB  = NN / RPB;        // blocks per batch (64 or 128)
    constexpr int PGRP = 8 * RPB;         // ax-agg thread group (64 or 32)
    constexpr int NCH  = THREADS / PGRP;  // ax-agg chunks (8 or 16)
    constexpr int MPC  = NN / NCH;        // m per chunk (64 or 32)

    __shared__ float a_lds[RPB * AST];   // adj tile (stride-swizzled)
    __shared__ float x_lds[NN * DD];     // x slice (linear [m][d])
    __shared__ float u_lds[8 * AHWS];    // union: ah wave-partials | g partials
    __shared__ float ax_part[THREADS];
    __shared__ float ah_lds[RPB * HH];
    __shared__ float ax_s[RPB * DD];
    __shared__ float hh_s[HH];
    __shared__ float z1_s[32];

    const int tid  = threadIdx.x;
    const int bid  = blockIdx.x;
    const int b    = bid / BPB;              // batch
    const int slot = bid % BPB;              // slot within batch
    const int n0   = slot * RPB;             // first owned row
    const int r_g  = (tid >> 6) & (RPB - 1); // gate row (dup waves if RPB<8)
    const int j_g  = tid & 63;

    // flat per-batch arrival counter (monotonic, relaxed, fire-and-forget add)
    unsigned* const broot = bar + b * CSTR;

    // ---- persistent per-thread state -------------------------------------
    const int half = tid >> 8;           // 0/1 (k-split for gate GEMM)
    const int jj   = tid & 255;          // gate column
    float whcol[36];
    if (half == 0) {
        #pragma unroll
        for (int k = 0; k < 36; ++k) whcol[k] = Wh[k * G4 + jj];
    } else {
        #pragma unroll
        for (int k = 0; k < 28; ++k) whcol[k] = Wh[(36 + k) * G4 + jj];
        #pragma unroll
        for (int d = 0; d < 8; ++d)  whcol[28 + d] = Wx[d * G4 + jj];
    }
    const float bias = (half == 0) ? bg[jj] : 0.f;
    const size_t sidx = ((size_t)b * NN + n0 + r_g) * HH + j_g;
    float c_reg = c0[sidx];              // dup waves hold harmless copies

    // ---- stage adj(0) [RPBx512], x(0) [512x8] -----------------------------
    {
        const float* ab = adj + (((size_t)b * SS + 0) * NN + n0) * NN;
        const float* xb = x + ((size_t)b * SS + 0) * (NN * DD);
        f32x4 pa0 = *(const f32x4*)(ab + tid * 4);
        f32x4 px0 = *(const f32x4*)(xb + tid * 4);
        f32x4 px1 = *(const f32x4*)(xb + 2048 + tid * 4);
        const int f0 = tid * 4;
        *(f32x4*)(a_lds + (f0 >> 9) * AST + (f0 & 511)) = pa0;
        if constexpr (RPB == 8) {
            f32x4 pa1 = *(const f32x4*)(ab + 2048 + tid * 4);
            const int f1 = 2048 + tid * 4;
            *(f32x4*)(a_lds + (f1 >> 9) * AST + (f1 & 511)) = pa1;
        }
        *(f32x4*)(x_lds + tid * 4) = px0;
        *(f32x4*)(x_lds + 2048 + tid * 4) = px1;
    }
    __syncthreads();

    // ---- reg prefetch t=1 ----
    f32x4 qa0, qa1, qx0, qx1;
    {
        const float* ab = adj + (((size_t)b * SS + 1) * NN + n0) * NN;
        const float* xb = x + ((size_t)b * SS + 1) * (NN * DD);
        qa0 = *(const f32x4*)(ab + tid * 4);
        if constexpr (RPB == 8) qa1 = *(const f32x4*)(ab + 2048 + tid * 4);
        qx0 = *(const f32x4*)(xb + tid * 4);
        qx1 = *(const f32x4*)(xb + 2048 + tid * 4);
    }

    // ---- x-agg partials for t=0: thread=(mg2,rr,d) ------------------------
    {
        const int d = tid & 7, rr = (tid >> 3) & (RPB - 1), mg2 = tid / PGRP;
        const float* ar = a_lds + rr * AST + mg2 * MPC;
        const float* xr = x_lds + mg2 * MPC * DD + d;
        float s = 0.f;
        #pragma unroll
        for (int mi = 0; mi < MPC; ++mi) s = fmaf(ar[mi], xr[mi * 8], s);
        ax_part[tid] = s;
    }

    const float* hp = h0;
    float* hd = hB;

    const int c4 = (tid & 15) * 4;
    const int m0 = (tid >> 4) * 16;      // 32 groups x 16 rows = all 512 m

    // ---- main recurrence -------------------------------------------------
    for (int t = 0; t < SS; ++t) {
        // phase A: 16 h-row loads (IC-coherent), pipelined with FMA chunks
        f32x4 hv[16];
        {
            const float* hpb = hp + (size_t)b * NN * HH;
            const unsigned long long hbase =
                (unsigned long long)(const void*)(hpb + (size_t)m0 * HH + c4);
#define HLOAD(I, OFFS) \
            asm volatile("global_load_dwordx4 %0, %1, off offset:" OFFS " sc0 sc1" \
                         : "=v"(hv[I]) : "v"(hbase) : "memory")
            HLOAD(0, "0");     HLOAD(1, "256");   HLOAD(2, "512");   HLOAD(3, "768");
            HLOAD(4, "1024");  HLOAD(5, "1280");  HLOAD(6, "1536");  HLOAD(7, "1792");
            HLOAD(8, "2048");  HLOAD(9, "2304");  HLOAD(10, "2560"); HLOAD(11, "2816");
            HLOAD(12, "3072"); HLOAD(13, "3328"); HLOAD(14, "3584"); HLOAD(15, "3840");
#undef HLOAD
        }
        // per-thread RPB-row x 4-col tile over this lane group's 16 m
        {
            f32x4 acc[RPB];
            #pragma unroll
            for (int r = 0; r < RPB; ++r) acc[r] = f32x4{0.f, 0.f, 0.f, 0.f};
#define AH_CHUNK(MI4) \
            { \
                _Pragma("unroll") \
                for (int r = 0; r < RPB; ++r) { \
                    const f32x4 a4 = *(const f32x4*)(a_lds + r * AST + m0 + (MI4)); \
                    vfma(acc[r], a4.x, hv[(MI4) + 0]); \
                    vfma(acc[r], a4.y, hv[(MI4) + 1]); \
                    vfma(acc[r], a4.z, hv[(MI4) + 2]); \
                    vfma(acc[r], a4.w, hv[(MI4) + 3]); \
                } \
            }
            // <=4 older prefetch loads may be outstanding; vmcnt(12) covers
            // them plus hv[0..3] (oldest-first), conservatively correct.
            asm volatile("s_waitcnt vmcnt(12)" ::: "memory");
            __builtin_amdgcn_sched_barrier(0);
            AH_CHUNK(0)
            asm volatile("s_waitcnt vmcnt(8)" ::: "memory");
            __builtin_amdgcn_sched_barrier(0);
            AH_CHUNK(4)
            asm volatile("s_waitcnt vmcnt(4)" ::: "memory");
            __builtin_amdgcn_sched_barrier(0);
            AH_CHUNK(8)
            asm volatile("s_waitcnt vmcnt(0)" ::: "memory");
            __builtin_amdgcn_sched_barrier(0);
            AH_CHUNK(12)
#undef AH_CHUNK
            #pragma unroll
            for (int r = 0; r < RPB; ++r) {
                acc[r].x += __shfl_xor(acc[r].x, 16); acc[r].y += __shfl_xor(acc[r].y, 16);
                acc[r].z += __shfl_xor(acc[r].z, 16); acc[r].w += __shfl_xor(acc[r].w, 16);
                acc[r].x += __shfl_xor(acc[r].x, 32); acc[r].y += __shfl_xor(acc[r].y, 32);
                acc[r].z += __shfl_xor(acc[r].z, 32); acc[r].w += __shfl_xor(acc[r].w, 32);
            }
            if ((tid & 48) == 0) {
                const int w = tid >> 6;
                #pragma unroll
                for (int r = 0; r < RPB; ++r)
                    *(f32x4*)(u_lds + w * AHWS + r * 64 + c4) = acc[r];
            }
        }
        __syncthreads();   // barrier A

        // reduce wave partials -> ah_lds [RPBx64] / ax_s [RPBx8]
        {
            if (tid < RPB * HH) {
                float s = 0.f;
                #pragma unroll
                for (int w2 = 0; w2 < 8; ++w2) s += u_lds[w2 * AHWS + tid];
                ah_lds[tid] = s;
            }
            if (tid < PGRP) {
                float s2 = 0.f;
                #pragma unroll
                for (int c2 = 0; c2 < NCH; ++c2) s2 += ax_part[c2 * PGRP + tid];
                ax_s[tid] = s2;
            }
        }
        __syncthreads();   // barrier B

        // phase B: g[r][jj] = ah@Wh + ax@Wx + b (36 / 28+8 split over halves)
        {
            float g[RPB];
            #pragma unroll
            for (int r = 0; r < RPB; ++r) g[r] = bias;
            if (half == 0) {
                #pragma unroll
                for (int k4 = 0; k4 < 36; k4 += 4) {
                    #pragma unroll
                    for (int r = 0; r < RPB; ++r) {
                        const f32x4 a4 = *(const f32x4*)(ah_lds + r * 64 + k4);
                        g[r] = fmaf(a4.x, whcol[k4 + 0], g[r]);
                        g[r] = fmaf(a4.y, whcol[k4 + 1], g[r]);
                        g[r] = fmaf(a4.z, whcol[k4 + 2], g[r]);
                        g[r] = fmaf(a4.w, whcol[k4 + 3], g[r]);
                    }
                }
            } else {
                #pragma unroll
                for (int k4 = 0; k4 < 28; k4 += 4) {
                    #pragma unroll
                    for (int r = 0; r < RPB; ++r) {
                        const f32x4 a4 = *(const f32x4*)(ah_lds + r * 64 + 36 + k4);
                        g[r] = fmaf(a4.x, whcol[k4 + 0], g[r]);
                        g[r] = fmaf(a4.y, whcol[k4 + 1], g[r]);
                        g[r] = fmaf(a4.z, whcol[k4 + 2], g[r]);
                        g[r] = fmaf(a4.w, whcol[k4 + 3], g[r]);
                    }
                }
                #pragma unroll
                for (int d4 = 0; d4 < 8; d4 += 4) {
                    #pragma unroll
                    for (int r = 0; r < RPB; ++r) {
                        const f32x4 a4 = *(const f32x4*)(ax_s + r * 8 + d4);
                        g[r] = fmaf(a4.x, whcol[28 + d4 + 0], g[r]);
                        g[r] = fmaf(a4.y, whcol[28 + d4 + 1], g[r]);
                        g[r] = fmaf(a4.z, whcol[28 + d4 + 2], g[r]);
                        g[r] = fmaf(a4.w, whcol[28 + d4 + 3], g[r]);
                    }
                }
            }
            #pragma unroll
            for (int r = 0; r < RPB; ++r) u_lds[(half * RPB + r) * 256 + jj] = g[r];
        }
        __syncthreads();   // barrier C

        // gates + state update (rows 0..RPB-1; extra waves compute duplicates)
        float hn;
        {
            const float gi = u_lds[r_g * 256 + j_g]       + u_lds[(RPB + r_g) * 256 + j_g];
            const float gf = u_lds[r_g * 256 + 64 + j_g]  + u_lds[(RPB + r_g) * 256 + 64 + j_g];
            const float go = u_lds[r_g * 256 + 128 + j_g] + u_lds[(RPB + r_g) * 256 + 128 + j_g];
            const float gg = u_lds[r_g * 256 + 192 + j_g] + u_lds[(RPB + r_g) * 256 + 192 + j_g];
            const float ig = sigm_f(gi);
            const float fg = sigm_f(gf);
            const float og = sigm_f(go);
            const float gt = tanh_f(gg);
            c_reg = fg * c_reg + ig * gt;
            hn = og * tanh_f(c_reg);
        }
        if (t == SS - 1) {
            if (slot == 0 && tid < 64) hh_s[tid] = hn;   // wave 0 owns node 0
            break;
        }
        // write-through h store (one wave per owned row)
        if ((tid >> 6) < RPB) {
            const unsigned long long haddr = (unsigned long long)(const void*)(hd + sidx);
            asm volatile("global_store_dword %0, %1, off sc0 sc1"
                         :: "v"(haddr), "v"(hn) : "memory");
        }

        // stage t+1 LDS from regs (drain overlapped below)
        {
            const int f0 = tid * 4;
            *(f32x4*)(a_lds + (f0 >> 9) * AST + (f0 & 511)) = qa0;
            if constexpr (RPB == 8) {
                const int f1 = 2048 + tid * 4;
                *(f32x4*)(a_lds + (f1 >> 9) * AST + (f1 & 511)) = qa1;
            }
            *(f32x4*)(x_lds + tid * 4) = qx0;
            *(f32x4*)(x_lds + 2048 + tid * 4) = qx1;
        }
        asm volatile("s_waitcnt vmcnt(0)" ::: "memory");
        __syncthreads();   // staging done + all h stores of this block in IC

        // arrive EARLY (tid0): single fire-and-forget relaxed add
        if (tid == 0)
            __hip_atomic_fetch_add(broot, 1u, __ATOMIC_RELAXED, __HIP_MEMORY_SCOPE_AGENT);

        // reg prefetch t+2 (lands during next step)
        {
            const int t2 = (t + 2 < SS) ? t + 2 : SS - 1;
            const float* ab = adj + (((size_t)b * SS + t2) * NN + n0) * NN;
            const float* xb = x + ((size_t)b * SS + t2) * (NN * DD);
            qa0 = *(const f32x4*)(ab + tid * 4);
            if constexpr (RPB == 8) qa1 = *(const f32x4*)(ab + 2048 + tid * 4);
            qx0 = *(const f32x4*)(xb + tid * 4);
            qx1 = *(const f32x4*)(xb + 2048 + tid * 4);
        }

        // x-agg partials for t+1 (fills the arrival-propagation window)
        {
            const int d = tid & 7, rr = (tid >> 3) & (RPB - 1), mg2 = tid / PGRP;
            const float* ar = a_lds + rr * AST + mg2 * MPC;
            const float* xr = x_lds + mg2 * MPC * DD + d;
            float s = 0.f;
            #pragma unroll
            for (int mi = 0; mi < MPC; ++mi) s = fmaf(ar[mi], xr[mi * 8], s);
            ax_part[tid] = s;
        }

        // poll LATE (tid0): BPB*(t+1) arrivals == all h(t) of this batch in IC
        if (tid == 0) {
            const unsigned tgt = (unsigned)BPB * (unsigned)(t + 1);
            while (__hip_atomic_load(broot, __ATOMIC_RELAXED, __HIP_MEMORY_SCOPE_AGENT) < tgt)
                __builtin_amdgcn_s_sleep(1);
        }
        __syncthreads();
        __builtin_amdgcn_sched_barrier(0);

        hp = hd;
        hd = (hd == hA) ? hB : hA;
    }

    // ---- per-batch readout head (block owning node 0 of each batch) ------
    if (slot == 0) {
        __syncthreads();
        if (tid < 32) {
            float s = b1[tid];
            #pragma unroll
            for (int j = 0; j < 64; ++j) s = fmaf(hh_s[j], W1[j * 32 + tid], s);
            z1_s[tid] = fmaxf(s, 0.f);
        }
        __syncthreads();
        if (tid < OUTK) {
            float s = b2[tid];
            #pragma unroll
            for (int k = 0; k < 32; ++k) s = fmaf(z1_s[k], W2[k * 24 + tid], s);
            out[b * OUTK + tid] = s;
        }
    }
}

// ---------------------------------------------------------------------------
extern "C" void kernel_launch(void* const* d_in, const int* in_sizes, int n_in,
                              void* d_out, int out_size, void* d_ws, size_t ws_size,
                              hipStream_t stream) {
    const float* x   = (const float*)d_in[0];
    const float* adj = (const float*)d_in[1];
    const float* h0  = (const float*)d_in[2];
    const float* c0  = (const float*)d_in[3];
    const float* Wx  = (const float*)d_in[4];
    const float* Wh  = (const float*)d_in[5];
    const float* bg  = (const float*)d_in[6];
    const float* W1  = (const float*)d_in[7];
    const float* b1  = (const float*)d_in[8];
    const float* W2  = (const float*)d_in[9];
    const float* b2  = (const float*)d_in[10];
    float* out = (float*)d_out;

    const int NE = BB * NN * HH;              // 131072 floats per h buffer
    float* ws = (float*)d_ws;
    float* hA = ws;
    float* hB = ws + NE;
    unsigned* bar = (unsigned*)(ws + 2 * NE);

    bar_init<<<1, 256, 0, stream>>>(bar);

    void* args[] = { (void*)&x, (void*)&adj, (void*)&h0, (void*)&c0,
                     (void*)&Wx, (void*)&Wh, (void*)&bg,
                     (void*)&W1, (void*)&b1, (void*)&W2, (void*)&b2,
                     (void*)&out, (void*)&hA, (void*)&hB, (void*)&bar };

    // Occupancy-gated grid choice: only use the 512-block (2/CU) partition if
    // the runtime's own occupancy arithmetic guarantees co-residency; else run
    // the proven 256-block (1/CU) partition. Host-only query; capture-safe.
    static int occ4 = -1;
    if (occ4 < 0) {
        int n = 0;
        if (hipOccupancyMaxActiveBlocksPerMultiprocessor(
                &n, reinterpret_cast<const void*>(gnn_lstm_persist<4>),
                THREADS, 0) != hipSuccess)
            n = 0;
        occ4 = n;
    }
    if (occ4 >= 2) {
        (void)hipLaunchCooperativeKernel((void*)gnn_lstm_persist<4>,
                                         dim3(BB * (NN / 4)), dim3(THREADS),
                                         args, 0, stream);
    } else {
        (void)hipLaunchCooperativeKernel((void*)gnn_lstm_persist<8>,
                                         dim3(BB * (NN / 8)), dim3(THREADS),
                                         args, 0, stream);
    }
}

// Round 11
// 837.957 us; speedup vs baseline: 2.2630x; 2.2630x over previous
//
#include <hip/hip_runtime.h>
#include <math.h>

// Problem constants
#define BB   4
#define SS   96
#define NN   512
#define DD   8
#define HH   64
#define G4   256    // 4*H
#define OUTK 24

#define THREADS 512
#define AST     580   // a_lds row stride
#define AHWS    516   // u_lds per-wave stride
#define CSTR    64    // u32 stride per batch counter (256 B line)
#define BARSZ   (BB * CSTR)

typedef float f32x4 __attribute__((ext_vector_type(4)));

// ---------------------------------------------------------------------------
__global__ void bar_init(unsigned* __restrict__ bar) {
    const int i = blockIdx.x * 256 + threadIdx.x;
    if (i < BARSZ) bar[i] = 0u;
}

__device__ __forceinline__ float sigm_f(float v) { return 1.f / (1.f + __expf(-v)); }
__device__ __forceinline__ float tanh_f(float v) { return 1.f - 2.f / (__expf(2.f * v) + 1.f); }

__device__ __forceinline__ void vfma(f32x4& d, float s, f32x4 v) {
    d.x = fmaf(s, v.x, d.x); d.y = fmaf(s, v.y, d.y);
    d.z = fmaf(s, v.z, d.z); d.w = fmaf(s, v.w, d.w);
}

// ---------------------------------------------------------------------------
// RPB=8: 256 blocks, 1/CU — byte-identical to the proven R6 kernel (staged
//        vmcnt ledger valid: 128 VGPR, no spills, measured 807 us).
// RPB=4: 512 blocks, 2/CU (CU pairs host different batches -> decorrelated
//        stall windows). NO counted vmcnt: one vmcnt(0) drain after the h
//        burst, correct regardless of compiler spill traffic (R9 lesson).
// Both under __launch_bounds__(512,2): empirical VGPR cap 128 (R10 lesson:
// (512,4) caps at 64 and spills catastrophically).
template<int RPB>
__global__ __launch_bounds__(THREADS, 2) void gnn_lstm_persist(
    const float* __restrict__ x,    // [B][S][N][D]
    const float* __restrict__ adj,  // [B][S][N][N]
    const float* __restrict__ h0,   // [B][N][H]
    const float* __restrict__ c0,   // [B][N][H]
    const float* __restrict__ Wx,   // [D][256]
    const float* __restrict__ Wh,   // [H][256]
    const float* __restrict__ bg,   // [256]
    const float* __restrict__ W1, const float* __restrict__ b1,
    const float* __restrict__ W2, const float* __restrict__ b2,
    float* __restrict__ out,        // [4][24]
    float* __restrict__ hA, float* __restrict__ hB,
    unsigned* __restrict__ bar)
{
    constexpr int BPB  = NN / RPB;        // blocks per batch (64 or 128)
    constexpr int PGRP = 8 * RPB;         // ax-agg thread group (64 or 32)
    constexpr int NCH  = THREADS / PGRP;  // ax-agg chunks (8 or 16)
    constexpr int MPC  = NN / NCH;        // m per chunk (64 or 32)

    __shared__ float a_lds[RPB * AST];   // adj tile (stride-swizzled)
    __shared__ float x_lds[NN * DD];     // x slice (linear [m][d])
    __shared__ float u_lds[8 * AHWS];    // union: ah wave-partials | g partials
    __shared__ float ax_part[THREADS];
    __shared__ float ah_lds[RPB * HH];
    __shared__ float ax_s[RPB * DD];
    __shared__ float hh_s[HH];
    __shared__ float z1_s[32];

    const int tid  = threadIdx.x;
    const int bid  = blockIdx.x;
    const int b    = bid / BPB;              // batch
    const int slot = bid % BPB;              // slot within batch
    const int n0   = slot * RPB;             // first owned row
    const int r_g  = (tid >> 6) & (RPB - 1); // gate row (dup waves if RPB<8)
    const int j_g  = tid & 63;

    // flat per-batch arrival counter (monotonic, relaxed, fire-and-forget add)
    unsigned* const broot = bar + b * CSTR;

    // ---- persistent per-thread state -------------------------------------
    const int half = tid >> 8;           // 0/1 (k-split for gate GEMM)
    const int jj   = tid & 255;          // gate column
    float whcol[36];
    if (half == 0) {
        #pragma unroll
        for (int k = 0; k < 36; ++k) whcol[k] = Wh[k * G4 + jj];
    } else {
        #pragma unroll
        for (int k = 0; k < 28; ++k) whcol[k] = Wh[(36 + k) * G4 + jj];
        #pragma unroll
        for (int d = 0; d < 8; ++d)  whcol[28 + d] = Wx[d * G4 + jj];
    }
    const float bias = (half == 0) ? bg[jj] : 0.f;
    const size_t sidx = ((size_t)b * NN + n0 + r_g) * HH + j_g;
    float c_reg = c0[sidx];              // dup waves hold harmless copies

    // ---- stage adj(0) [RPBx512], x(0) [512x8] -----------------------------
    {
        const float* ab = adj + (((size_t)b * SS + 0) * NN + n0) * NN;
        const float* xb = x + ((size_t)b * SS + 0) * (NN * DD);
        f32x4 pa0 = *(const f32x4*)(ab + tid * 4);
        f32x4 px0 = *(const f32x4*)(xb + tid * 4);
        f32x4 px1 = *(const f32x4*)(xb + 2048 + tid * 4);
        const int f0 = tid * 4;
        *(f32x4*)(a_lds + (f0 >> 9) * AST + (f0 & 511)) = pa0;
        if constexpr (RPB == 8) {
            f32x4 pa1 = *(const f32x4*)(ab + 2048 + tid * 4);
            const int f1 = 2048 + tid * 4;
            *(f32x4*)(a_lds + (f1 >> 9) * AST + (f1 & 511)) = pa1;
        }
        *(f32x4*)(x_lds + tid * 4) = px0;
        *(f32x4*)(x_lds + 2048 + tid * 4) = px1;
    }
    __syncthreads();

    // ---- reg prefetch t=1 ----
    f32x4 qa0, qa1, qx0, qx1;
    {
        const float* ab = adj + (((size_t)b * SS + 1) * NN + n0) * NN;
        const float* xb = x + ((size_t)b * SS + 1) * (NN * DD);
        qa0 = *(const f32x4*)(ab + tid * 4);
        if constexpr (RPB == 8) qa1 = *(const f32x4*)(ab + 2048 + tid * 4);
        qx0 = *(const f32x4*)(xb + tid * 4);
        qx1 = *(const f32x4*)(xb + 2048 + tid * 4);
    }

    // ---- x-agg partials for t=0: thread=(mg2,rr,d) ------------------------
    {
        const int d = tid & 7, rr = (tid >> 3) & (RPB - 1), mg2 = tid / PGRP;
        const float* ar = a_lds + rr * AST + mg2 * MPC;
        const float* xr = x_lds + mg2 * MPC * DD + d;
        float s = 0.f;
        #pragma unroll
        for (int mi = 0; mi < MPC; ++mi) s = fmaf(ar[mi], xr[mi * 8], s);
        ax_part[tid] = s;
    }

    const float* hp = h0;
    float* hd = hB;

    const int c4 = (tid & 15) * 4;
    const int m0 = (tid >> 4) * 16;      // 32 groups x 16 rows = all 512 m

    // ---- main recurrence -------------------------------------------------
    for (int t = 0; t < SS; ++t) {
        // phase A: 16 h-row loads (IC-coherent)
        f32x4 hv[16];
        {
            const float* hpb = hp + (size_t)b * NN * HH;
            const unsigned long long hbase =
                (unsigned long long)(const void*)(hpb + (size_t)m0 * HH + c4);
#define HLOAD(I, OFFS) \
            asm volatile("global_load_dwordx4 %0, %1, off offset:" OFFS " sc0 sc1" \
                         : "=v"(hv[I]) : "v"(hbase) : "memory")
            HLOAD(0, "0");     HLOAD(1, "256");   HLOAD(2, "512");   HLOAD(3, "768");
            HLOAD(4, "1024");  HLOAD(5, "1280");  HLOAD(6, "1536");  HLOAD(7, "1792");
            HLOAD(8, "2048");  HLOAD(9, "2304");  HLOAD(10, "2560"); HLOAD(11, "2816");
            HLOAD(12, "3072"); HLOAD(13, "3328"); HLOAD(14, "3584"); HLOAD(15, "3840");
#undef HLOAD
        }
        // per-thread RPB-row x 4-col tile over this lane group's 16 m
        {
            f32x4 acc[RPB];
            #pragma unroll
            for (int r = 0; r < RPB; ++r) acc[r] = f32x4{0.f, 0.f, 0.f, 0.f};
#define AH_CHUNK(MI4) \
            { \
                _Pragma("unroll") \
                for (int r = 0; r < RPB; ++r) { \
                    const f32x4 a4 = *(const f32x4*)(a_lds + r * AST + m0 + (MI4)); \
                    vfma(acc[r], a4.x, hv[(MI4) + 0]); \
                    vfma(acc[r], a4.y, hv[(MI4) + 1]); \
                    vfma(acc[r], a4.z, hv[(MI4) + 2]); \
                    vfma(acc[r], a4.w, hv[(MI4) + 3]); \
                } \
            }
            if constexpr (RPB == 8) {
                // Proven R6 staged ledger (valid: 128 VGPR, no spills).
                // <=4 older prefetch loads outstanding; vmcnt(12) covers them
                // plus hv[0..3] (oldest-first), conservatively correct.
                asm volatile("s_waitcnt vmcnt(12)" ::: "memory");
                __builtin_amdgcn_sched_barrier(0);
                AH_CHUNK(0)
                asm volatile("s_waitcnt vmcnt(8)" ::: "memory");
                __builtin_amdgcn_sched_barrier(0);
                AH_CHUNK(4)
                asm volatile("s_waitcnt vmcnt(4)" ::: "memory");
                __builtin_amdgcn_sched_barrier(0);
                AH_CHUNK(8)
                asm volatile("s_waitcnt vmcnt(0)" ::: "memory");
                __builtin_amdgcn_sched_barrier(0);
                AH_CHUNK(12)
            } else {
                // Spill-proof: full drain before ANY hv use. Correct even if
                // the compiler interleaves scratch ops (they also count in
                // vmcnt, and vmcnt(0) waits for everything). TLP from the
                // co-resident block hides the unoverlapped burst latency.
                asm volatile("s_waitcnt vmcnt(0)" ::: "memory");
                __builtin_amdgcn_sched_barrier(0);
                AH_CHUNK(0)
                AH_CHUNK(4)
                AH_CHUNK(8)
                AH_CHUNK(12)
            }
#undef AH_CHUNK
            #pragma unroll
            for (int r = 0; r < RPB; ++r) {
                acc[r].x += __shfl_xor(acc[r].x, 16); acc[r].y += __shfl_xor(acc[r].y, 16);
                acc[r].z += __shfl_xor(acc[r].z, 16); acc[r].w += __shfl_xor(acc[r].w, 16);
                acc[r].x += __shfl_xor(acc[r].x, 32); acc[r].y += __shfl_xor(acc[r].y, 32);
                acc[r].z += __shfl_xor(acc[r].z, 32); acc[r].w += __shfl_xor(acc[r].w, 32);
            }
            if ((tid & 48) == 0) {
                const int w = tid >> 6;
                #pragma unroll
                for (int r = 0; r < RPB; ++r)
                    *(f32x4*)(u_lds + w * AHWS + r * 64 + c4) = acc[r];
            }
        }
        __syncthreads();   // barrier A

        // reduce wave partials -> ah_lds [RPBx64] / ax_s [RPBx8]
        {
            if (tid < RPB * HH) {
                float s = 0.f;
                #pragma unroll
                for (int w2 = 0; w2 < 8; ++w2) s += u_lds[w2 * AHWS + tid];
                ah_lds[tid] = s;
            }
            if (tid < PGRP) {
                float s2 = 0.f;
                #pragma unroll
                for (int c2 = 0; c2 < NCH; ++c2) s2 += ax_part[c2 * PGRP + tid];
                ax_s[tid] = s2;
            }
        }
        __syncthreads();   // barrier B

        // phase B: g[r][jj] = ah@Wh + ax@Wx + b (36 / 28+8 split over halves)
        {
            float g[RPB];
            #pragma unroll
            for (int r = 0; r < RPB; ++r) g[r] = bias;
            if (half == 0) {
                #pragma unroll
                for (int k4 = 0; k4 < 36; k4 += 4) {
                    #pragma unroll
                    for (int r = 0; r < RPB; ++r) {
                        const f32x4 a4 = *(const f32x4*)(ah_lds + r * 64 + k4);
                        g[r] = fmaf(a4.x, whcol[k4 + 0], g[r]);
                        g[r] = fmaf(a4.y, whcol[k4 + 1], g[r]);
                        g[r] = fmaf(a4.z, whcol[k4 + 2], g[r]);
                        g[r] = fmaf(a4.w, whcol[k4 + 3], g[r]);
                    }
                }
            } else {
                #pragma unroll
                for (int k4 = 0; k4 < 28; k4 += 4) {
                    #pragma unroll
                    for (int r = 0; r < RPB; ++r) {
                        const f32x4 a4 = *(const f32x4*)(ah_lds + r * 64 + 36 + k4);
                        g[r] = fmaf(a4.x, whcol[k4 + 0], g[r]);
                        g[r] = fmaf(a4.y, whcol[k4 + 1], g[r]);
                        g[r] = fmaf(a4.z, whcol[k4 + 2], g[r]);
                        g[r] = fmaf(a4.w, whcol[k4 + 3], g[r]);
                    }
                }
                #pragma unroll
                for (int d4 = 0; d4 < 8; d4 += 4) {
                    #pragma unroll
                    for (int r = 0; r < RPB; ++r) {
                        const f32x4 a4 = *(const f32x4*)(ax_s + r * 8 + d4);
                        g[r] = fmaf(a4.x, whcol[28 + d4 + 0], g[r]);
                        g[r] = fmaf(a4.y, whcol[28 + d4 + 1], g[r]);
                        g[r] = fmaf(a4.z, whcol[28 + d4 + 2], g[r]);
                        g[r] = fmaf(a4.w, whcol[28 + d4 + 3], g[r]);
                    }
                }
            }
            #pragma unroll
            for (int r = 0; r < RPB; ++r) u_lds[(half * RPB + r) * 256 + jj] = g[r];
        }
        __syncthreads();   // barrier C

        // gates + state update (rows 0..RPB-1; extra waves compute duplicates)
        float hn;
        {
            const float gi = u_lds[r_g * 256 + j_g]       + u_lds[(RPB + r_g) * 256 + j_g];
            const float gf = u_lds[r_g * 256 + 64 + j_g]  + u_lds[(RPB + r_g) * 256 + 64 + j_g];
            const float go = u_lds[r_g * 256 + 128 + j_g] + u_lds[(RPB + r_g) * 256 + 128 + j_g];
            const float gg = u_lds[r_g * 256 + 192 + j_g] + u_lds[(RPB + r_g) * 256 + 192 + j_g];
            const float ig = sigm_f(gi);
            const float fg = sigm_f(gf);
            const float og = sigm_f(go);
            const float gt = tanh_f(gg);
            c_reg = fg * c_reg + ig * gt;
            hn = og * tanh_f(c_reg);
        }
        if (t == SS - 1) {
            if (slot == 0 && tid < 64) hh_s[tid] = hn;   // wave 0 owns node 0
            break;
        }
        // write-through h store (one wave per owned row)
        if ((tid >> 6) < RPB) {
            const unsigned long long haddr = (unsigned long long)(const void*)(hd + sidx);
            asm volatile("global_store_dword %0, %1, off sc0 sc1"
                         :: "v"(haddr), "v"(hn) : "memory");
        }

        // stage t+1 LDS from regs (drain overlapped below)
        {
            const int f0 = tid * 4;
            *(f32x4*)(a_lds + (f0 >> 9) * AST + (f0 & 511)) = qa0;
            if constexpr (RPB == 8) {
                const int f1 = 2048 + tid * 4;
                *(f32x4*)(a_lds + (f1 >> 9) * AST + (f1 & 511)) = qa1;
            }
            *(f32x4*)(x_lds + tid * 4) = qx0;
            *(f32x4*)(x_lds + 2048 + tid * 4) = qx1;
        }
        asm volatile("s_waitcnt vmcnt(0)" ::: "memory");
        __syncthreads();   // staging done + all h stores of this block in IC

        // arrive EARLY (tid0): single fire-and-forget relaxed add
        if (tid == 0)
            __hip_atomic_fetch_add(broot, 1u, __ATOMIC_RELAXED, __HIP_MEMORY_SCOPE_AGENT);

        // reg prefetch t+2 (lands during next step)
        {
            const int t2 = (t + 2 < SS) ? t + 2 : SS - 1;
            const float* ab = adj + (((size_t)b * SS + t2) * NN + n0) * NN;
            const float* xb = x + ((size_t)b * SS + t2) * (NN * DD);
            qa0 = *(const f32x4*)(ab + tid * 4);
            if constexpr (RPB == 8) qa1 = *(const f32x4*)(ab + 2048 + tid * 4);
            qx0 = *(const f32x4*)(xb + tid * 4);
            qx1 = *(const f32x4*)(xb + 2048 + tid * 4);
        }

        // x-agg partials for t+1 (fills the arrival-propagation window)
        {
            const int d = tid & 7, rr = (tid >> 3) & (RPB - 1), mg2 = tid / PGRP;
            const float* ar = a_lds + rr * AST + mg2 * MPC;
            const float* xr = x_lds + mg2 * MPC * DD + d;
            float s = 0.f;
            #pragma unroll
            for (int mi = 0; mi < MPC; ++mi) s = fmaf(ar[mi], xr[mi * 8], s);
            ax_part[tid] = s;
        }

        // poll LATE (tid0): BPB*(t+1) arrivals == all h(t) of this batch in IC
        if (tid == 0) {
            const unsigned tgt = (unsigned)BPB * (unsigned)(t + 1);
            while (__hip_atomic_load(broot, __ATOMIC_RELAXED, __HIP_MEMORY_SCOPE_AGENT) < tgt)
                __builtin_amdgcn_s_sleep(1);
        }
        __syncthreads();
        __builtin_amdgcn_sched_barrier(0);

        hp = hd;
        hd = (hd == hA) ? hB : hA;
    }

    // ---- per-batch readout head (block owning node 0 of each batch) ------
    if (slot == 0) {
        __syncthreads();
        if (tid < 32) {
            float s = b1[tid];
            #pragma unroll
            for (int j = 0; j < 64; ++j) s = fmaf(hh_s[j], W1[j * 32 + tid], s);
            z1_s[tid] = fmaxf(s, 0.f);
        }
        __syncthreads();
        if (tid < OUTK) {
            float s = b2[tid];
            #pragma unroll
            for (int k = 0; k < 32; ++k) s = fmaf(z1_s[k], W2[k * 24 + tid], s);
            out[b * OUTK + tid] = s;
        }
    }
}

// ---------------------------------------------------------------------------
extern "C" void kernel_launch(void* const* d_in, const int* in_sizes, int n_in,
                              void* d_out, int out_size, void* d_ws, size_t ws_size,
                              hipStream_t stream) {
    const float* x   = (const float*)d_in[0];
    const float* adj = (const float*)d_in[1];
    const float* h0  = (const float*)d_in[2];
    const float* c0  = (const float*)d_in[3];
    const float* Wx  = (const float*)d_in[4];
    const float* Wh  = (const float*)d_in[5];
    const float* bg  = (const float*)d_in[6];
    const float* W1  = (const float*)d_in[7];
    const float* b1  = (const float*)d_in[8];
    const float* W2  = (const float*)d_in[9];
    const float* b2  = (const float*)d_in[10];
    float* out = (float*)d_out;

    const int NE = BB * NN * HH;              // 131072 floats per h buffer
    float* ws = (float*)d_ws;
    float* hA = ws;
    float* hB = ws + NE;
    unsigned* bar = (unsigned*)(ws + 2 * NE);

    bar_init<<<1, 256, 0, stream>>>(bar);

    void* args[] = { (void*)&x, (void*)&adj, (void*)&h0, (void*)&c0,
                     (void*)&Wx, (void*)&Wh, (void*)&bg,
                     (void*)&W1, (void*)&b1, (void*)&W2, (void*)&b2,
                     (void*)&out, (void*)&hA, (void*)&hB, (void*)&bar };

    // Occupancy-gated grid choice: only launch the 512-block (2/CU) partition
    // if the runtime occupancy guarantees co-residency; else the proven
    // 256-block (1/CU) kernel. Host-only query; capture-safe.
    static int occ4 = -1;
    if (occ4 < 0) {
        int n = 0;
        if (hipOccupancyMaxActiveBlocksPerMultiprocessor(
                &n, reinterpret_cast<const void*>(gnn_lstm_persist<4>),
                THREADS, 0) != hipSuccess)
            n = 0;
        occ4 = n;
    }
    if (occ4 >= 2) {
        (void)hipLaunchCooperativeKernel((void*)gnn_lstm_persist<4>,
                                         dim3(BB * (NN / 4)), dim3(THREADS),
                                         args, 0, stream);
    } else {
        (void)hipLaunchCooperativeKernel((void*)gnn_lstm_persist<8>,
                                         dim3(BB * (NN / 8)), dim3(THREADS),
                                         args, 0, stream);
    }
}

// Round 12
// 740.120 us; speedup vs baseline: 2.5621x; 1.1322x over previous
//
#include <hip/hip_runtime.h>
#include <math.h>

// Problem constants
#define BB   4
#define SS   96
#define NN   512
#define DD   8
#define HH   64
#define G4   256    // 4*H
#define OUTK 24

#define THREADS 512
#define NBLK    256   // 4 batches x 64 blocks, cooperative (co-resident, 1/CU)
#define RPB     8     // adj rows per block
#define AST     580   // a_lds row stride
#define AHWS    516   // u_lds per-wave stride
#define FSLOT   16    // u32 per producer flag (64 B line)
#define FSTR    (64 * FSLOT)      // flags per batch
#define BARSZ   (BB * FSTR)       // 4096 u32

typedef float f32x4 __attribute__((ext_vector_type(4)));

// ---------------------------------------------------------------------------
__global__ void bar_init(unsigned* __restrict__ bar) {
    const int i = blockIdx.x * 256 + threadIdx.x;
    if (i < BARSZ) bar[i] = 0u;
}

__device__ __forceinline__ float sigm_f(float v) { return 1.f / (1.f + __expf(-v)); }
__device__ __forceinline__ float tanh_f(float v) { return 1.f - 2.f / (__expf(2.f * v) + 1.f); }

__device__ __forceinline__ void vfma(f32x4& d, float s, f32x4 v) {
    d.x = fmaf(s, v.x, d.x); d.y = fmaf(s, v.y, d.y);
    d.z = fmaf(s, v.z, d.z); d.w = fmaf(s, v.w, d.w);
}

// ---------------------------------------------------------------------------
__global__ __launch_bounds__(THREADS, 2) void gnn_lstm_persist(
    const float* __restrict__ x,    // [B][S][N][D]
    const float* __restrict__ adj,  // [B][S][N][N]
    const float* __restrict__ h0,   // [B][N][H]
    const float* __restrict__ c0,   // [B][N][H]
    const float* __restrict__ Wx,   // [D][256]
    const float* __restrict__ Wh,   // [H][256]
    const float* __restrict__ bg,   // [256]
    const float* __restrict__ W1, const float* __restrict__ b1,
    const float* __restrict__ W2, const float* __restrict__ b2,
    float* __restrict__ out,        // [4][24]
    float* __restrict__ hA, float* __restrict__ hB,
    unsigned* __restrict__ bar)
{
    __shared__ float a_lds[RPB * AST];   // adj tile (stride-swizzled)
    __shared__ float x_lds[NN * DD];     // x slice
    __shared__ float u_lds[8 * AHWS];    // union: ah wave-partials | g partials
    __shared__ float ax_part[THREADS];
    __shared__ float ah_lds[RPB * HH];
    __shared__ float ax_s[RPB * DD];
    __shared__ float hh_s[HH];
    __shared__ float z1_s[32];

    const int tid  = threadIdx.x;
    const int bid  = blockIdx.x;
    const int b    = bid >> 6;           // batch
    const int slot = bid & 63;           // 0..63 within batch
    const int n0   = slot * RPB;
    const int r_g  = tid >> 6;           // wave id = owned row
    const int j_g  = tid & 63;

    // per-producer dataflow flags (monotonic step counters, via IC).
    // Wave w consumes h rows [64w,64w+64) = producers [8w,8w+8);
    // lane l of wave w watches producer 8w + (l&7).
    unsigned* const pfb    = bar + b * FSTR;
    const int pw           = ((tid >> 6) << 3) + (tid & 7);
    unsigned* const fwatch = pfb + pw * FSLOT;
    unsigned* const fpost  = pfb + slot * FSLOT;
    const bool selfw       = (pw == slot);   // never IC-wait on own flag

    // ---- persistent per-thread state -------------------------------------
    const int half = tid >> 8;           // 0/1
    const int jj   = tid & 255;          // gate column
    float whcol[36];
    if (half == 0) {
        #pragma unroll
        for (int k = 0; k < 36; ++k) whcol[k] = Wh[k * G4 + jj];
    } else {
        #pragma unroll
        for (int k = 0; k < 28; ++k) whcol[k] = Wh[(36 + k) * G4 + jj];
        #pragma unroll
        for (int d = 0; d < 8; ++d)  whcol[28 + d] = Wx[d * G4 + jj];
    }
    const float bias = (half == 0) ? bg[jj] : 0.f;
    const size_t sidx = ((size_t)b * NN + n0 + r_g) * HH + j_g;
    float c_reg = c0[sidx];

    // ---- stage adj(0), x(0) ----------------------------------------------
    {
        const float* ab = adj + (((size_t)b * SS + 0) * NN + n0) * NN;
        const float* xb = x + ((size_t)b * SS + 0) * (NN * DD);
        f32x4 pa0 = *(const f32x4*)(ab + tid * 4);
        f32x4 pa1 = *(const f32x4*)(ab + 2048 + tid * 4);
        f32x4 px0 = *(const f32x4*)(xb + tid * 4);
        f32x4 px1 = *(const f32x4*)(xb + 2048 + tid * 4);
        const int f0 = tid * 4;
        *(f32x4*)(a_lds + (f0 >> 9) * AST + (f0 & 511)) = pa0;
        const int f1 = 2048 + tid * 4;
        *(f32x4*)(a_lds + (f1 >> 9) * AST + (f1 & 511)) = pa1;
        *(f32x4*)(x_lds + tid * 4) = px0;
        *(f32x4*)(x_lds + 2048 + tid * 4) = px1;
    }
    __syncthreads();

    // ---- reg prefetch t=1 ----
    f32x4 qa0, qa1, qx0, qx1;
    {
        const float* ab = adj + (((size_t)b * SS + 1) * NN + n0) * NN;
        const float* xb = x + ((size_t)b * SS + 1) * (NN * DD);
        qa0 = *(const f32x4*)(ab + tid * 4);
        qa1 = *(const f32x4*)(ab + 2048 + tid * 4);
        qx0 = *(const f32x4*)(xb + tid * 4);
        qx1 = *(const f32x4*)(xb + 2048 + tid * 4);
    }

    // ---- x-agg partials for t=0 ----
    {
        const int d = tid & 7, rr = (tid >> 3) & 7, mg2 = tid >> 6;
        const float* ar = a_lds + rr * AST + mg2 * 64;
        const float* xr = x_lds + mg2 * 512 + d;
        float s = 0.f;
        #pragma unroll
        for (int mi = 0; mi < 64; ++mi) s = fmaf(ar[mi], xr[mi * 8], s);
        ax_part[tid] = s;
    }

    const float* hp = h0;
    float* hd = hB;

    const int c4 = (tid & 15) * 4;
    const int m0 = (tid >> 4) * 16;

    // ---- main recurrence -------------------------------------------------
    for (int t = 0; t < SS; ++t) {
        // dataflow gate: each wave waits only for ITS 8 producers of h(t).
        // (Compiler manages the atomic-load waits; never touches hand vmcnt.)
        if (t) {
            for (;;) {
                unsigned fv = __hip_atomic_load(fwatch, __ATOMIC_RELAXED,
                                                __HIP_MEMORY_SCOPE_AGENT);
                if (selfw) fv = (unsigned)t;   // own stores already drained
                if (__all(fv >= (unsigned)t)) break;
                __builtin_amdgcn_s_sleep(1);
            }
            __builtin_amdgcn_sched_barrier(0);
        }

        // phase A: two-stage h-row burst (spill-immune: only vmcnt(0) drains).
        f32x4 hv[8], hw[8];
        {
            const float* hpb = hp + (size_t)b * NN * HH;
            const unsigned long long hbase =
                (unsigned long long)(const void*)(hpb + (size_t)m0 * HH + c4);
#define HLV(I, OFFS) \
            asm volatile("global_load_dwordx4 %0, %1, off offset:" OFFS " sc0 sc1" \
                         : "=v"(hv[I]) : "v"(hbase) : "memory")
#define HLW(I, OFFS) \
            asm volatile("global_load_dwordx4 %0, %1, off offset:" OFFS " sc0 sc1" \
                         : "=v"(hw[I]) : "v"(hbase) : "memory")
            HLV(0, "0");    HLV(1, "256");  HLV(2, "512");  HLV(3, "768");
            HLV(4, "1024"); HLV(5, "1280"); HLV(6, "1536"); HLV(7, "1792");
            // drain stage 1 (also retires any older prefetch/flag traffic)
            asm volatile("s_waitcnt vmcnt(0)" ::: "memory");
            __builtin_amdgcn_sched_barrier(0);
            // issue stage 2 — its latency hides under the hv FMA block below
            HLW(0, "2048"); HLW(1, "2304"); HLW(2, "2560"); HLW(3, "2816");
            HLW(4, "3072"); HLW(5, "3328"); HLW(6, "3584"); HLW(7, "3840");
#undef HLV
#undef HLW
        }
        {
            f32x4 acc[8];
            #pragma unroll
            for (int r = 0; r < 8; ++r) acc[r] = f32x4{0.f, 0.f, 0.f, 0.f};
#define AH_CHUNK(ARR, MI4, BASE) \
            { \
                _Pragma("unroll") \
                for (int r = 0; r < 8; ++r) { \
                    const f32x4 a4 = *(const f32x4*)(a_lds + r * AST + m0 + (MI4)); \
                    vfma(acc[r], a4.x, ARR[(MI4) - (BASE) + 0]); \
                    vfma(acc[r], a4.y, ARR[(MI4) - (BASE) + 1]); \
                    vfma(acc[r], a4.z, ARR[(MI4) - (BASE) + 2]); \
                    vfma(acc[r], a4.w, ARR[(MI4) - (BASE) + 3]); \
                } \
            }
            AH_CHUNK(hv, 0, 0)
            AH_CHUNK(hv, 4, 0)
            // drain stage 2 (overlapped with the two chunks above)
            asm volatile("s_waitcnt vmcnt(0)" ::: "memory");
            __builtin_amdgcn_sched_barrier(0);
            AH_CHUNK(hw, 8, 8)
            AH_CHUNK(hw, 12, 8)
#undef AH_CHUNK
            #pragma unroll
            for (int r = 0; r < 8; ++r) {
                acc[r].x += __shfl_xor(acc[r].x, 16); acc[r].y += __shfl_xor(acc[r].y, 16);
                acc[r].z += __shfl_xor(acc[r].z, 16); acc[r].w += __shfl_xor(acc[r].w, 16);
                acc[r].x += __shfl_xor(acc[r].x, 32); acc[r].y += __shfl_xor(acc[r].y, 32);
                acc[r].z += __shfl_xor(acc[r].z, 32); acc[r].w += __shfl_xor(acc[r].w, 32);
            }
            if ((tid & 48) == 0) {
                const int w = tid >> 6;
                #pragma unroll
                for (int r = 0; r < 8; ++r)
                    *(f32x4*)(u_lds + w * AHWS + r * 64 + c4) = acc[r];
            }
        }
        __syncthreads();   // barrier A

        // reduce wave partials -> ah_lds / ax_s
        {
            float s = 0.f;
            #pragma unroll
            for (int w2 = 0; w2 < 8; ++w2) s += u_lds[w2 * AHWS + tid];
            ah_lds[tid] = s;
            if (tid < 64) {
                float s2 = 0.f;
                #pragma unroll
                for (int w2 = 0; w2 < 8; ++w2) s2 += ax_part[w2 * 64 + tid];
                ax_s[tid] = s2;
            }
        }
        __syncthreads();   // barrier B

        // phase B: g[r][jj] = ah@Wh + ax@Wx + b (36 / 28+8 split over halves)
        {
            float g[8];
            #pragma unroll
            for (int r = 0; r < 8; ++r) g[r] = bias;
            if (half == 0) {
                #pragma unroll
                for (int k4 = 0; k4 < 36; k4 += 4) {
                    #pragma unroll
                    for (int r = 0; r < 8; ++r) {
                        const f32x4 a4 = *(const f32x4*)(ah_lds + r * 64 + k4);
                        g[r] = fmaf(a4.x, whcol[k4 + 0], g[r]);
                        g[r] = fmaf(a4.y, whcol[k4 + 1], g[r]);
                        g[r] = fmaf(a4.z, whcol[k4 + 2], g[r]);
                        g[r] = fmaf(a4.w, whcol[k4 + 3], g[r]);
                    }
                }
            } else {
                #pragma unroll
                for (int k4 = 0; k4 < 28; k4 += 4) {
                    #pragma unroll
                    for (int r = 0; r < 8; ++r) {
                        const f32x4 a4 = *(const f32x4*)(ah_lds + r * 64 + 36 + k4);
                        g[r] = fmaf(a4.x, whcol[k4 + 0], g[r]);
                        g[r] = fmaf(a4.y, whcol[k4 + 1], g[r]);
                        g[r] = fmaf(a4.z, whcol[k4 + 2], g[r]);
                        g[r] = fmaf(a4.w, whcol[k4 + 3], g[r]);
                    }
                }
                #pragma unroll
                for (int d4 = 0; d4 < 8; d4 += 4) {
                    #pragma unroll
                    for (int r = 0; r < 8; ++r) {
                        const f32x4 a4 = *(const f32x4*)(ax_s + r * 8 + d4);
                        g[r] = fmaf(a4.x, whcol[28 + d4 + 0], g[r]);
                        g[r] = fmaf(a4.y, whcol[28 + d4 + 1], g[r]);
                        g[r] = fmaf(a4.z, whcol[28 + d4 + 2], g[r]);
                        g[r] = fmaf(a4.w, whcol[28 + d4 + 3], g[r]);
                    }
                }
            }
            #pragma unroll
            for (int r = 0; r < 8; ++r) u_lds[(half * 8 + r) * 256 + jj] = g[r];
        }
        __syncthreads();   // barrier C

        // gates + state update
        float hn;
        {
            const float gi = u_lds[r_g * 256 + j_g]       + u_lds[(8 + r_g) * 256 + j_g];
            const float gf = u_lds[r_g * 256 + 64 + j_g]  + u_lds[(8 + r_g) * 256 + 64 + j_g];
            const float go = u_lds[r_g * 256 + 128 + j_g] + u_lds[(8 + r_g) * 256 + 128 + j_g];
            const float gg = u_lds[r_g * 256 + 192 + j_g] + u_lds[(8 + r_g) * 256 + 192 + j_g];
            const float ig = sigm_f(gi);
            const float fg = sigm_f(gf);
            const float og = sigm_f(go);
            const float gt = tanh_f(gg);
            c_reg = fg * c_reg + ig * gt;
            hn = og * tanh_f(c_reg);
        }
        if (t == SS - 1) {
            if (slot == 0 && tid < 64) hh_s[tid] = hn;   // wave 0 owns node 0
            break;
        }
        // write-through h store (issue only; drain overlapped with staging)
        {
            const unsigned long long haddr = (unsigned long long)(const void*)(hd + sidx);
            asm volatile("global_store_dword %0, %1, off sc0 sc1"
                         :: "v"(haddr), "v"(hn) : "memory");
        }

        // stage t+1 LDS from regs (no wave of this block still reads a/x_lds)
        {
            const int f0 = tid * 4;
            *(f32x4*)(a_lds + (f0 >> 9) * AST + (f0 & 511)) = qa0;
            const int f1 = 2048 + tid * 4;
            *(f32x4*)(a_lds + (f1 >> 9) * AST + (f1 & 511)) = qa1;
            *(f32x4*)(x_lds + tid * 4) = qx0;
            *(f32x4*)(x_lds + 2048 + tid * 4) = qx1;
        }
        // drain the write-through store (overlapped with the LDS staging above)
        asm volatile("s_waitcnt vmcnt(0)" ::: "memory");
        __syncthreads();   // staging done + all h stores of this block in IC

        // publish: single monotonic flag; consumed per-wave by all blocks
        if (tid == 0)
            __hip_atomic_store(fpost, (unsigned)(t + 1), __ATOMIC_RELAXED,
                               __HIP_MEMORY_SCOPE_AGENT);

        // reg prefetch t+2 (lands during next step)
        {
            const int t2 = (t + 2 < SS) ? t + 2 : SS - 1;
            const float* ab = adj + (((size_t)b * SS + t2) * NN + n0) * NN;
            const float* xb = x + ((size_t)b * SS + t2) * (NN * DD);
            qa0 = *(const f32x4*)(ab + tid * 4);
            qa1 = *(const f32x4*)(ab + 2048 + tid * 4);
            qx0 = *(const f32x4*)(xb + tid * 4);
            qx1 = *(const f32x4*)(xb + 2048 + tid * 4);
        }

        // x-agg partials for t+1 (fills the producer-skew window)
        {
            const int d = tid & 7, rr = (tid >> 3) & 7, mg2 = tid >> 6;
            const float* ar = a_lds + rr * AST + mg2 * 64;
            const float* xr = x_lds + mg2 * 512 + d;
            float s = 0.f;
            #pragma unroll
            for (int mi = 0; mi < 64; ++mi) s = fmaf(ar[mi], xr[mi * 8], s);
            ax_part[tid] = s;
        }

        hp = hd;
        hd = (hd == hA) ? hB : hA;
    }

    // ---- per-batch readout head (block owning node 0 of each batch) ------
    if (slot == 0) {
        __syncthreads();
        if (tid < 32) {
            float s = b1[tid];
            #pragma unroll
            for (int j = 0; j < 64; ++j) s = fmaf(hh_s[j], W1[j * 32 + tid], s);
            z1_s[tid] = fmaxf(s, 0.f);
        }
        __syncthreads();
        if (tid < OUTK) {
            float s = b2[tid];
            #pragma unroll
            for (int k = 0; k < 32; ++k) s = fmaf(z1_s[k], W2[k * 24 + tid], s);
            out[b * OUTK + tid] = s;
        }
    }
}

// ---------------------------------------------------------------------------
extern "C" void kernel_launch(void* const* d_in, const int* in_sizes, int n_in,
                              void* d_out, int out_size, void* d_ws, size_t ws_size,
                              hipStream_t stream) {
    const float* x   = (const float*)d_in[0];
    const float* adj = (const float*)d_in[1];
    const float* h0  = (const float*)d_in[2];
    const float* c0  = (const float*)d_in[3];
    const float* Wx  = (const float*)d_in[4];
    const float* Wh  = (const float*)d_in[5];
    const float* bg  = (const float*)d_in[6];
    const float* W1  = (const float*)d_in[7];
    const float* b1  = (const float*)d_in[8];
    const float* W2  = (const float*)d_in[9];
    const float* b2  = (const float*)d_in[10];
    float* out = (float*)d_out;

    const int NE = BB * NN * HH;              // 131072 floats per h buffer
    float* ws = (float*)d_ws;
    float* hA = ws;
    float* hB = ws + NE;
    unsigned* bar = (unsigned*)(ws + 2 * NE);

    bar_init<<<(BARSZ + 255) / 256, 256, 0, stream>>>(bar);

    void* args[] = { (void*)&x, (void*)&adj, (void*)&h0, (void*)&c0,
                     (void*)&Wx, (void*)&Wh, (void*)&bg,
                     (void*)&W1, (void*)&b1, (void*)&W2, (void*)&b2,
                     (void*)&out, (void*)&hA, (void*)&hB, (void*)&bar };
    hipLaunchCooperativeKernel((void*)gnn_lstm_persist,
                               dim3(NBLK), dim3(THREADS), args, 0, stream);
}

// Round 13
// 717.005 us; speedup vs baseline: 2.6447x; 1.0322x over previous
//
#include <hip/hip_runtime.h>
#include <math.h>

// Problem constants
#define BB   4
#define SS   96
#define NN   512
#define DD   8
#define HH   64
#define G4   256    // 4*H
#define OUTK 24

#define THREADS 512
#define NBLK    256   // 4 batches x 64 blocks, cooperative (co-resident, 1/CU)
#define RPB     8     // adj rows per block
#define AST     580   // a_lds row stride
#define AHWS    516   // u_lds per-wave stride
#define FSLOT   16    // u32 per producer flag (64 B line)
#define FSTR    (64 * FSLOT)      // flags per batch
#define BARSZ   (BB * FSTR)       // 4096 u32

typedef float f32x4 __attribute__((ext_vector_type(4)));

// ---------------------------------------------------------------------------
__global__ void bar_init(unsigned* __restrict__ bar) {
    const int i = blockIdx.x * 256 + threadIdx.x;
    if (i < BARSZ) bar[i] = 0u;
}

__device__ __forceinline__ float sigm_f(float v) { return 1.f / (1.f + __expf(-v)); }
__device__ __forceinline__ float tanh_f(float v) { return 1.f - 2.f / (__expf(2.f * v) + 1.f); }

__device__ __forceinline__ void vfma(f32x4& d, float s, f32x4 v) {
    d.x = fmaf(s, v.x, d.x); d.y = fmaf(s, v.y, d.y);
    d.z = fmaf(s, v.z, d.z); d.w = fmaf(s, v.w, d.w);
}

// ---------------------------------------------------------------------------
__global__ __launch_bounds__(THREADS, 2) void gnn_lstm_persist(
    const float* __restrict__ x,    // [B][S][N][D]
    const float* __restrict__ adj,  // [B][S][N][N]
    const float* __restrict__ h0,   // [B][N][H]
    const float* __restrict__ c0,   // [B][N][H]
    const float* __restrict__ Wx,   // [D][256]
    const float* __restrict__ Wh,   // [H][256]
    const float* __restrict__ bg,   // [256]
    const float* __restrict__ W1, const float* __restrict__ b1,
    const float* __restrict__ W2, const float* __restrict__ b2,
    float* __restrict__ out,        // [4][24]
    float* __restrict__ hA, float* __restrict__ hB,
    unsigned* __restrict__ bar)
{
    __shared__ float a_lds[RPB * AST];   // adj tile (stride-swizzled)
    __shared__ float x_lds[NN * DD];     // x slice
    __shared__ float u_lds[8 * AHWS];    // union: ah wave-partials | g partials
    __shared__ float ax_part[THREADS];
    __shared__ float ah_lds[RPB * HH];
    __shared__ float ax_s[RPB * DD];
    __shared__ float hh_s[HH];
    __shared__ float z1_s[32];

    const int tid  = threadIdx.x;
    const int bid  = blockIdx.x;
    const int b    = bid >> 6;           // batch
    const int slot = bid & 63;           // 0..63 within batch
    const int n0   = slot * RPB;
    const int r_g  = tid >> 6;           // wave id = owned row
    const int j_g  = tid & 63;

    // per-producer dataflow flags (monotonic step counters, via IC).
    // Wave w consumes h rows [64w,64w+64) = producers [8w,8w+8);
    // lane l of wave w watches producer 8w + (l&7).
    unsigned* const pfb    = bar + b * FSTR;
    const int pw           = ((tid >> 6) << 3) + (tid & 7);
    unsigned* const fwatch = pfb + pw * FSLOT;
    unsigned* const fpost  = pfb + slot * FSLOT;
    const bool selfw       = (pw == slot);   // never IC-wait on own flag

    // ---- persistent per-thread state -------------------------------------
    const int half = tid >> 8;           // 0/1
    const int jj   = tid & 255;          // gate column
    float whcol[36];
    if (half == 0) {
        #pragma unroll
        for (int k = 0; k < 36; ++k) whcol[k] = Wh[k * G4 + jj];
    } else {
        #pragma unroll
        for (int k = 0; k < 28; ++k) whcol[k] = Wh[(36 + k) * G4 + jj];
        #pragma unroll
        for (int d = 0; d < 8; ++d)  whcol[28 + d] = Wx[d * G4 + jj];
    }
    const float bias = (half == 0) ? bg[jj] : 0.f;
    const size_t sidx = ((size_t)b * NN + n0 + r_g) * HH + j_g;
    float c_reg = c0[sidx];

    // x-agg addressing (thread = (mg2, rr, d))
    const int xd  = tid & 7;
    const int xrr = (tid >> 3) & 7;
    const int xmg = tid >> 6;

    // ---- stage adj(0), x(0) ----------------------------------------------
    {
        const float* ab = adj + (((size_t)b * SS + 0) * NN + n0) * NN;
        const float* xb = x + ((size_t)b * SS + 0) * (NN * DD);
        f32x4 pa0 = *(const f32x4*)(ab + tid * 4);
        f32x4 pa1 = *(const f32x4*)(ab + 2048 + tid * 4);
        f32x4 px0 = *(const f32x4*)(xb + tid * 4);
        f32x4 px1 = *(const f32x4*)(xb + 2048 + tid * 4);
        const int f0 = tid * 4;
        *(f32x4*)(a_lds + (f0 >> 9) * AST + (f0 & 511)) = pa0;
        const int f1 = 2048 + tid * 4;
        *(f32x4*)(a_lds + (f1 >> 9) * AST + (f1 & 511)) = pa1;
        *(f32x4*)(x_lds + tid * 4) = px0;
        *(f32x4*)(x_lds + 2048 + tid * 4) = px1;
    }
    __syncthreads();

    // ---- reg prefetch t=1 ----
    f32x4 qa0, qa1, qx0, qx1;
    {
        const float* ab = adj + (((size_t)b * SS + 1) * NN + n0) * NN;
        const float* xb = x + ((size_t)b * SS + 1) * (NN * DD);
        qa0 = *(const f32x4*)(ab + tid * 4);
        qa1 = *(const f32x4*)(ab + 2048 + tid * 4);
        qx0 = *(const f32x4*)(xb + tid * 4);
        qx1 = *(const f32x4*)(xb + 2048 + tid * 4);
    }

    // ---- x-agg HALF1 (mi 0..31) for t=0; half2 runs in phase A of t=0 ----
    float ax_half;
    {
        const float* ar = a_lds + xrr * AST + xmg * 64;
        const float* xr = x_lds + xmg * 512 + xd;
        float s = 0.f;
        #pragma unroll
        for (int mi = 0; mi < 32; ++mi) s = fmaf(ar[mi], xr[mi * 8], s);
        ax_half = s;
    }

    const float* hp = h0;
    float* hd = hB;

    const int c4 = (tid & 15) * 4;
    const int m0 = (tid >> 4) * 16;

    // ---- main recurrence -------------------------------------------------
    for (int t = 0; t < SS; ++t) {
        // dataflow gate: each wave waits only for ITS 8 producers of h(t).
        // (Compiler manages the atomic-load waits; never touches hand vmcnt.)
        if (t) {
            for (;;) {
                unsigned fv = __hip_atomic_load(fwatch, __ATOMIC_RELAXED,
                                                __HIP_MEMORY_SCOPE_AGENT);
                if (selfw) fv = (unsigned)t;   // own stores already drained
                if (__all(fv >= (unsigned)t)) break;
                __builtin_amdgcn_s_sleep(1);
            }
            __builtin_amdgcn_sched_barrier(0);
        }

        // phase A: two-stage h-row burst (spill-immune: only vmcnt(0) drains).
        f32x4 hv[8], hw[8];
        {
            const float* hpb = hp + (size_t)b * NN * HH;
            const unsigned long long hbase =
                (unsigned long long)(const void*)(hpb + (size_t)m0 * HH + c4);
#define HLV(I, OFFS) \
            asm volatile("global_load_dwordx4 %0, %1, off offset:" OFFS " sc0 sc1" \
                         : "=v"(hv[I]) : "v"(hbase) : "memory")
#define HLW(I, OFFS) \
            asm volatile("global_load_dwordx4 %0, %1, off offset:" OFFS " sc0 sc1" \
                         : "=v"(hw[I]) : "v"(hbase) : "memory")
            HLV(0, "0");    HLV(1, "256");  HLV(2, "512");  HLV(3, "768");
            HLV(4, "1024"); HLV(5, "1280"); HLV(6, "1536"); HLV(7, "1792");
            // x-agg HALF2 (mi 32..63) fills the stage-1 latency window.
            // Pure LDS/VALU (lgkmcnt only) -> vmcnt ledger untouched; a_lds/
            // x_lds hold step t's tile (staged+barriered last iteration).
            // Continues ax_half so the 0..63 summation order is unchanged.
            {
                const float* ar = a_lds + xrr * AST + xmg * 64;
                const float* xr = x_lds + xmg * 512 + xd;
                float s = ax_half;
                #pragma unroll
                for (int mi = 32; mi < 64; ++mi) s = fmaf(ar[mi], xr[mi * 8], s);
                ax_part[tid] = s;
            }
            // drain stage 1 (also retires any older prefetch/flag traffic)
            asm volatile("s_waitcnt vmcnt(0)" ::: "memory");
            __builtin_amdgcn_sched_barrier(0);
            // issue stage 2 — its latency hides under the hv FMA block below
            HLW(0, "2048"); HLW(1, "2304"); HLW(2, "2560"); HLW(3, "2816");
            HLW(4, "3072"); HLW(5, "3328"); HLW(6, "3584"); HLW(7, "3840");
#undef HLV
#undef HLW
        }
        {
            f32x4 acc[8];
            #pragma unroll
            for (int r = 0; r < 8; ++r) acc[r] = f32x4{0.f, 0.f, 0.f, 0.f};
#define AH_CHUNK(ARR, MI4, BASE) \
            { \
                _Pragma("unroll") \
                for (int r = 0; r < 8; ++r) { \
                    const f32x4 a4 = *(const f32x4*)(a_lds + r * AST + m0 + (MI4)); \
                    vfma(acc[r], a4.x, ARR[(MI4) - (BASE) + 0]); \
                    vfma(acc[r], a4.y, ARR[(MI4) - (BASE) + 1]); \
                    vfma(acc[r], a4.z, ARR[(MI4) - (BASE) + 2]); \
                    vfma(acc[r], a4.w, ARR[(MI4) - (BASE) + 3]); \
                } \
            }
            AH_CHUNK(hv, 0, 0)
            AH_CHUNK(hv, 4, 0)
            // drain stage 2 (overlapped with the two chunks above)
            asm volatile("s_waitcnt vmcnt(0)" ::: "memory");
            __builtin_amdgcn_sched_barrier(0);
            AH_CHUNK(hw, 8, 8)
            AH_CHUNK(hw, 12, 8)
#undef AH_CHUNK
            #pragma unroll
            for (int r = 0; r < 8; ++r) {
                acc[r].x += __shfl_xor(acc[r].x, 16); acc[r].y += __shfl_xor(acc[r].y, 16);
                acc[r].z += __shfl_xor(acc[r].z, 16); acc[r].w += __shfl_xor(acc[r].w, 16);
                acc[r].x += __shfl_xor(acc[r].x, 32); acc[r].y += __shfl_xor(acc[r].y, 32);
                acc[r].z += __shfl_xor(acc[r].z, 32); acc[r].w += __shfl_xor(acc[r].w, 32);
            }
            if ((tid & 48) == 0) {
                const int w = tid >> 6;
                #pragma unroll
                for (int r = 0; r < 8; ++r)
                    *(f32x4*)(u_lds + w * AHWS + r * 64 + c4) = acc[r];
            }
        }
        __syncthreads();   // barrier A

        // reduce wave partials -> ah_lds / ax_s
        {
            float s = 0.f;
            #pragma unroll
            for (int w2 = 0; w2 < 8; ++w2) s += u_lds[w2 * AHWS + tid];
            ah_lds[tid] = s;
            if (tid < 64) {
                float s2 = 0.f;
                #pragma unroll
                for (int w2 = 0; w2 < 8; ++w2) s2 += ax_part[w2 * 64 + tid];
                ax_s[tid] = s2;
            }
        }
        __syncthreads();   // barrier B

        // phase B: g[r][jj] = ah@Wh + ax@Wx + b (36 / 28+8 split over halves)
        {
            float g[8];
            #pragma unroll
            for (int r = 0; r < 8; ++r) g[r] = bias;
            if (half == 0) {
                #pragma unroll
                for (int k4 = 0; k4 < 36; k4 += 4) {
                    #pragma unroll
                    for (int r = 0; r < 8; ++r) {
                        const f32x4 a4 = *(const f32x4*)(ah_lds + r * 64 + k4);
                        g[r] = fmaf(a4.x, whcol[k4 + 0], g[r]);
                        g[r] = fmaf(a4.y, whcol[k4 + 1], g[r]);
                        g[r] = fmaf(a4.z, whcol[k4 + 2], g[r]);
                        g[r] = fmaf(a4.w, whcol[k4 + 3], g[r]);
                    }
                }
            } else {
                #pragma unroll
                for (int k4 = 0; k4 < 28; k4 += 4) {
                    #pragma unroll
                    for (int r = 0; r < 8; ++r) {
                        const f32x4 a4 = *(const f32x4*)(ah_lds + r * 64 + 36 + k4);
                        g[r] = fmaf(a4.x, whcol[k4 + 0], g[r]);
                        g[r] = fmaf(a4.y, whcol[k4 + 1], g[r]);
                        g[r] = fmaf(a4.z, whcol[k4 + 2], g[r]);
                        g[r] = fmaf(a4.w, whcol[k4 + 3], g[r]);
                    }
                }
                #pragma unroll
                for (int d4 = 0; d4 < 8; d4 += 4) {
                    #pragma unroll
                    for (int r = 0; r < 8; ++r) {
                        const f32x4 a4 = *(const f32x4*)(ax_s + r * 8 + d4);
                        g[r] = fmaf(a4.x, whcol[28 + d4 + 0], g[r]);
                        g[r] = fmaf(a4.y, whcol[28 + d4 + 1], g[r]);
                        g[r] = fmaf(a4.z, whcol[28 + d4 + 2], g[r]);
                        g[r] = fmaf(a4.w, whcol[28 + d4 + 3], g[r]);
                    }
                }
            }
            #pragma unroll
            for (int r = 0; r < 8; ++r) u_lds[(half * 8 + r) * 256 + jj] = g[r];
        }
        __syncthreads();   // barrier C

        // gates + state update
        float hn;
        {
            const float gi = u_lds[r_g * 256 + j_g]       + u_lds[(8 + r_g) * 256 + j_g];
            const float gf = u_lds[r_g * 256 + 64 + j_g]  + u_lds[(8 + r_g) * 256 + 64 + j_g];
            const float go = u_lds[r_g * 256 + 128 + j_g] + u_lds[(8 + r_g) * 256 + 128 + j_g];
            const float gg = u_lds[r_g * 256 + 192 + j_g] + u_lds[(8 + r_g) * 256 + 192 + j_g];
            const float ig = sigm_f(gi);
            const float fg = sigm_f(gf);
            const float og = sigm_f(go);
            const float gt = tanh_f(gg);
            c_reg = fg * c_reg + ig * gt;
            hn = og * tanh_f(c_reg);
        }
        if (t == SS - 1) {
            if (slot == 0 && tid < 64) hh_s[tid] = hn;   // wave 0 owns node 0
            break;
        }
        // write-through h store (issue only; drain overlapped with staging)
        {
            const unsigned long long haddr = (unsigned long long)(const void*)(hd + sidx);
            asm volatile("global_store_dword %0, %1, off sc0 sc1"
                         :: "v"(haddr), "v"(hn) : "memory");
        }

        // stage t+1 LDS from regs (no wave of this block still reads a/x_lds)
        {
            const int f0 = tid * 4;
            *(f32x4*)(a_lds + (f0 >> 9) * AST + (f0 & 511)) = qa0;
            const int f1 = 2048 + tid * 4;
            *(f32x4*)(a_lds + (f1 >> 9) * AST + (f1 & 511)) = qa1;
            *(f32x4*)(x_lds + tid * 4) = qx0;
            *(f32x4*)(x_lds + 2048 + tid * 4) = qx1;
        }
        // drain the write-through store (overlapped with the LDS staging above)
        asm volatile("s_waitcnt vmcnt(0)" ::: "memory");
        __syncthreads();   // staging done + all h stores of this block in IC

        // publish: single monotonic flag; consumed per-wave by all blocks
        if (tid == 0)
            __hip_atomic_store(fpost, (unsigned)(t + 1), __ATOMIC_RELAXED,
                               __HIP_MEMORY_SCOPE_AGENT);

        // reg prefetch t+2 (lands during next step)
        {
            const int t2 = (t + 2 < SS) ? t + 2 : SS - 1;
            const float* ab = adj + (((size_t)b * SS + t2) * NN + n0) * NN;
            const float* xb = x + ((size_t)b * SS + t2) * (NN * DD);
            qa0 = *(const f32x4*)(ab + tid * 4);
            qa1 = *(const f32x4*)(ab + 2048 + tid * 4);
            qx0 = *(const f32x4*)(xb + tid * 4);
            qx1 = *(const f32x4*)(xb + 2048 + tid * 4);
        }

        // x-agg HALF1 for t+1 (mi 0..31; fills the producer-skew window).
        // Half2 runs in next iteration's phase A, continuing ax_half.
        {
            const float* ar = a_lds + xrr * AST + xmg * 64;
            const float* xr = x_lds + xmg * 512 + xd;
            float s = 0.f;
            #pragma unroll
            for (int mi = 0; mi < 32; ++mi) s = fmaf(ar[mi], xr[mi * 8], s);
            ax_half = s;
        }

        hp = hd;
        hd = (hd == hA) ? hB : hA;
    }

    // ---- per-batch readout head (block owning node 0 of each batch) ------
    if (slot == 0) {
        __syncthreads();
        if (tid < 32) {
            float s = b1[tid];
            #pragma unroll
            for (int j = 0; j < 64; ++j) s = fmaf(hh_s[j], W1[j * 32 + tid], s);
            z1_s[tid] = fmaxf(s, 0.f);
        }
        __syncthreads();
        if (tid < OUTK) {
            float s = b2[tid];
            #pragma unroll
            for (int k = 0; k < 32; ++k) s = fmaf(z1_s[k], W2[k * 24 + tid], s);
            out[b * OUTK + tid] = s;
        }
    }
}

// ---------------------------------------------------------------------------
extern "C" void kernel_launch(void* const* d_in, const int* in_sizes, int n_in,
                              void* d_out, int out_size, void* d_ws, size_t ws_size,
                              hipStream_t stream) {
    const float* x   = (const float*)d_in[0];
    const float* adj = (const float*)d_in[1];
    const float* h0  = (const float*)d_in[2];
    const float* c0  = (const float*)d_in[3];
    const float* Wx  = (const float*)d_in[4];
    const float* Wh  = (const float*)d_in[5];
    const float* bg  = (const float*)d_in[6];
    const float* W1  = (const float*)d_in[7];
    const float* b1  = (const float*)d_in[8];
    const float* W2  = (const float*)d_in[9];
    const float* b2  = (const float*)d_in[10];
    float* out = (float*)d_out;

    const int NE = BB * NN * HH;              // 131072 floats per h buffer
    float* ws = (float*)d_ws;
    float* hA = ws;
    float* hB = ws + NE;
    unsigned* bar = (unsigned*)(ws + 2 * NE);

    bar_init<<<(BARSZ + 255) / 256, 256, 0, stream>>>(bar);

    void* args[] = { (void*)&x, (void*)&adj, (void*)&h0, (void*)&c0,
                     (void*)&Wx, (void*)&Wh, (void*)&bg,
                     (void*)&W1, (void*)&b1, (void*)&W2, (void*)&b2,
                     (void*)&out, (void*)&hA, (void*)&hB, (void*)&bar };
    hipLaunchCooperativeKernel((void*)gnn_lstm_persist,
                               dim3(NBLK), dim3(THREADS), args, 0, stream);
}